// Round 3
// baseline (80.530 us; speedup 1.0000x reference)
//
#include <hip/hip_runtime.h>
#include <hip/hip_bf16.h>
#include <stdint.h>

typedef __attribute__((ext_vector_type(8))) short short8;
typedef __attribute__((ext_vector_type(4))) float float4_t;

#define N_PTS 1024
#define G_DIM 620
#define G_PAD 640
#define F_DIM 20
#define H_DIM 150
#define H_PAD 160
#define K_WIN 128
#define OUT_C (K_WIN + 1)
#define BK 32
#define NSTEP 20           // d-steps of 32 over G_PAD
#define PSTR 80            // LDS row stride bytes (32 bf16 = 64B data + 16B pad)

__device__ __forceinline__ float bf2f(short u) {
  union { unsigned int i; float f; } x;
  x.i = ((unsigned int)(unsigned short)u) << 16;
  return x.f;
}
__device__ __forceinline__ short f2bf(float f) {
  union { float f; unsigned int i; } x; x.f = f;
  unsigned int u = x.i;
  u += 0x7FFFu + ((u >> 16) & 1u);   // RNE
  return (short)(u >> 16);
}
__device__ __forceinline__ short f2bf_hw(float f) {
  __hip_bfloat16 h = __float2bfloat16(f);
  union { __hip_bfloat16 h; short s; } u; u.h = h;
  return u.s;
}
__device__ __forceinline__ void gload_lds16(const void* g, void* l) {
  __builtin_amdgcn_global_load_lds(
      (const __attribute__((address_space(1))) unsigned int*)g,
      (__attribute__((address_space(3))) unsigned int*)l, 16, 0, 0);
}

// ---------------------------------------------------------------------------
// prep_pack: grid 321 x 256.
//  [0,256)  : g_bf [1024][640] bf16 (4 rows/block, vectorized)
//  [256,316): LDS-tiled transposes (32-d x 160-h tiles):
//             third 0 -> W1abT rows 0..159   (W1a^T)
//             third 1 -> W1abT rows 160..319 (W1b^T)
//             third 2 -> W1cT  [160][640]
//  [316,320): W2T [160][160] : W2T[m][k] = W2[k*150+m]
//  [320]    : deWT [160][32] bf16 : deWT[h][kk] = (dist_emb @ W1d)[kk][h], kk<9
// ---------------------------------------------------------------------------
__global__ void prep_pack(const float* __restrict__ g, const float* __restrict__ W1,
                          const float* __restrict__ W2, const float* __restrict__ dist_emb,
                          short* __restrict__ g_bf, short* __restrict__ W1cT,
                          short* __restrict__ W1abT, short* __restrict__ W2T,
                          short* __restrict__ deWT) {
  __shared__ float lds[32 * 165];     // 21.1 KB (transpose tiles)
  __shared__ float dw[9 * H_PAD];
  const int bx = blockIdx.x, tid = threadIdx.x;
  if (bx < 256) {
    const int n0 = bx * 4;
    for (int c = tid; c < 320; c += 256) {
      int r = c / 80, cc = c - r * 80;
      int n = n0 + r, d0 = cc * 8;
      short8 o;
      if (d0 + 8 <= G_DIM) {
        const float* src = g + n * G_DIM + d0;
        #pragma unroll
        for (int e = 0; e < 8; ++e) o[e] = f2bf(src[e]);
      } else {
        #pragma unroll
        for (int e = 0; e < 8; ++e) {
          int d = d0 + e;
          o[e] = (d < G_DIM) ? f2bf(g[n * G_DIM + d]) : (short)0;
        }
      }
      *(short8*)(g_bf + n * G_PAD + d0) = o;
    }
  } else if (bx < 316) {
    const int tb = bx - 256;
    const int third = tb / 20, dt = tb - third * 20;
    const int d0 = dt * 32;
    for (int c = tid; c < 1280; c += 256) {       // 32 d-rows x 40 chunks(4h)
      int dr = c / 40, ch4 = c - dr * 40;
      int dd = d0 + dr;
      int w1r = third * G_DIM + dd;
      #pragma unroll
      for (int e = 0; e < 4; ++e) {
        int h = ch4 * 4 + e;
        lds[dr * 165 + h] = (dd < G_DIM && h < H_DIM) ? W1[w1r * H_DIM + h] : 0.f;
      }
    }
    __syncthreads();
    short* outp = (third == 2) ? W1cT : (W1abT + third * H_PAD * G_PAD);
    for (int c = tid; c < 640; c += 256) {        // 160 h-rows x 4 chunks(8d)
      int h = c >> 2, ch = c & 3;
      short8 o;
      #pragma unroll
      for (int e = 0; e < 8; ++e) o[e] = f2bf(lds[(ch * 8 + e) * 165 + h]);
      *(short8*)(outp + h * G_PAD + d0 + ch * 8) = o;
    }
  } else if (bx < 320) {
    const int base = (bx - 316) * 6400;
    for (int c = tid; c < 6400; c += 256) {
      int q = base + c;
      int m = q / H_PAD, k = q - m * H_PAD;
      W2T[q] = (m < H_DIM && k < H_DIM) ? f2bf(W2[k * H_DIM + m]) : (short)0;
    }
  } else {
    for (int c = tid; c < 9 * H_PAD; c += 256) {
      int b = c / H_PAD, h = c - b * H_PAD;
      float acc = 0.f;
      if (h < H_DIM)
        for (int f = 0; f < F_DIM; ++f)
          acc += dist_emb[b * F_DIM + f] * W1[(3 * G_DIM + f) * H_DIM + h];
      dw[c] = acc;
    }
    __syncthreads();
    if (tid < H_PAD) {
      #pragma unroll
      for (int ch = 0; ch < 4; ++ch) {
        short8 o;
        #pragma unroll
        for (int e = 0; e < 8; ++e) {
          int kk = ch * 8 + e;
          o[e] = (kk < 9) ? f2bf(dw[kk * H_PAD + tid]) : (short)0;
        }
        *(short8*)(deWT + tid * 32 + ch * 8) = o;
      }
    }
  }
}

// ---------------------------------------------------------------------------
// prep_uv_mfma: y=0 -> U_bf (bf16, +b1) ; y=1 -> V (f32). 64 rows/block.
// ---------------------------------------------------------------------------
__global__ __launch_bounds__(256) void prep_uv_mfma(
    const short* __restrict__ g_bf, const short* __restrict__ W1abT,
    const float* __restrict__ b1, short* __restrict__ U_bf, float* __restrict__ V) {
  __shared__ __align__(16) char sA[64 * 128];
  __shared__ __align__(16) char sB[160 * 128];
  const int m0 = blockIdx.x * 64;
  const int yb = blockIdx.y * H_PAD;
  const int tid = threadIdx.x, lane = tid & 63, wid = tid >> 6;
  const int wm = wid >> 1, wn = wid & 1;
  const int lo4 = lane & 15, hi2 = lane >> 4;
  const int l8 = lane >> 3, c8 = lane & 7;
  const int xe = (c8 ^ (l8 & 7)) * 8;

  const float4_t fz = {0.f, 0.f, 0.f, 0.f};
  float4_t acc[2][5];
  #pragma unroll
  for (int a = 0; a < 2; ++a)
    #pragma unroll
    for (int b = 0; b < 5; ++b) acc[a][b] = fz;

  for (int step = 0; step < 10; ++step) {
    const int d0 = step * 64;
    #pragma unroll
    for (int cc = 0; cc < 2; ++cc) {
      int row = wid * 8 + cc * 32 + l8;
      gload_lds16(g_bf + (m0 + row) * G_PAD + d0 + xe, sA + (wid * 8 + cc * 32) * 128);
    }
    #pragma unroll
    for (int cc = 0; cc < 5; ++cc) {
      int row = wid * 8 + cc * 32 + l8;
      gload_lds16(W1abT + (yb + row) * G_PAD + d0 + xe, sB + (wid * 8 + cc * 32) * 128);
    }
    __syncthreads();
    #pragma unroll
    for (int ks = 0; ks < 2; ++ks) {
      const int kb = ks * 64 + 16 * hi2;
      short8 af[2], bq[5];
      #pragma unroll
      for (int mt = 0; mt < 2; ++mt) {
        int row = wm * 32 + mt * 16 + lo4;
        af[mt] = *((const short8*)(sA + row * 128 + (kb ^ ((row & 7) << 4))));
      }
      #pragma unroll
      for (int nt = 0; nt < 5; ++nt) {
        int row = wn * 80 + nt * 16 + lo4;
        bq[nt] = *((const short8*)(sB + row * 128 + (kb ^ ((row & 7) << 4))));
      }
      #pragma unroll
      for (int mt = 0; mt < 2; ++mt)
        #pragma unroll
        for (int nt = 0; nt < 5; ++nt)
          acc[mt][nt] = __builtin_amdgcn_mfma_f32_16x16x32_bf16(af[mt], bq[nt], acc[mt][nt], 0, 0, 0);
    }
    __syncthreads();
  }

  const bool isU = (blockIdx.y == 0);
  #pragma unroll
  for (int mt = 0; mt < 2; ++mt)
    #pragma unroll
    for (int r = 0; r < 4; ++r) {
      int m = m0 + wm * 32 + mt * 16 + hi2 * 4 + r;
      #pragma unroll
      for (int nt = 0; nt < 5; ++nt) {
        int h = wn * 80 + nt * 16 + lo4;
        float v = acc[mt][nt][r];
        if (isU) {
          v = (h < H_DIM) ? v + b1[h] : 0.f;
          U_bf[m * H_PAD + h] = f2bf(v);
        } else {
          V[m * H_PAD + h] = (h < H_DIM) ? v : 0.f;
        }
      }
    }
}

// ---------------------------------------------------------------------------
// pair_main: one block per i (XCD-swizzled). 4 waves (2M x 2N), 3 blocks/CU.
// Layer1: 20 steps BK=32 over G_PAD + 1 aug step folding U+b1+deW[bin].
// Reg-staged A (product) and B, dbuf LDS, 1 barrier/step.
// Layer2: h1(LDS) @ W2T(direct global), K=160, no staging barriers.
// ---------------------------------------------------------------------------
__global__ __launch_bounds__(256, 3) void pair_main(
    const short* __restrict__ g_bf, const short* __restrict__ W1cT,
    const short* __restrict__ W2T, const short* __restrict__ U_bf,
    const float* __restrict__ V, const short* __restrict__ deWT,
    const float* __restrict__ si, const int* __restrict__ i1,
    const int* __restrict__ i2, const float* __restrict__ W3,
    const float* __restrict__ b2, const float* __restrict__ b3,
    float* __restrict__ out) {
  __shared__ __align__(16) char smem[49152];   // stage (46080) | Hb (49152) union
  __shared__ __align__(16) short gi_s[G_PAD];
  __shared__ float sj_s[K_WIN];
  __shared__ int bin_s[K_WIN];
  __shared__ float s_buf[2][K_WIN];

  char* const P0 = smem;                 // 128*80 = 10240
  char* const P1 = smem + 10240;
  char* const B0 = smem + 20480;         // 160*80 = 12800
  char* const B1 = smem + 33280;
  char* const Hb = smem;                 // 3 x 16384 (after layer-1)

  const int bid = blockIdx.x;
  const int i = ((bid & 7) << 7) | (bid >> 3);   // XCD-bijective swizzle
  const int tid = threadIdx.x;
  const int lane = tid & 63;
  const int wid = tid >> 6;
  const int wm = wid >> 1, wn = wid & 1;
  const int lo4 = lane & 15, hi2 = lane >> 4;
  const int rA = tid >> 2;        // A/B row within first 64
  const int cA = tid & 3;         // chunk (8 elems)

  // ---- preamble ----
  if (tid < G_PAD / 8)
    ((short8*)gi_s)[tid] = ((const short8*)(g_bf + i * G_PAD))[tid];
  if (tid < K_WIN) {
    int jr = i - K_WIN + tid, jc = jr < 0 ? 0 : jr;
    int d = i2[i] - i1[jc];
    bin_s[tid] = (d >= 1) + (d >= 2) + (d >= 3) + (d >= 4) +
                 (d >= 8) + (d >= 16) + (d >= 32) + (d >= 64);
    sj_s[tid] = si[jc];
  }
  __syncthreads();

  // per-thread source bases
  int jr0 = i - K_WIN + rA;        int jc0 = jr0 < 0 ? 0 : jr0;
  int jr1 = i - K_WIN + rA + 64;   int jc1 = jr1 < 0 ? 0 : jr1;
  const short* gpA0 = g_bf + jc0 * G_PAD + cA * 8;
  const short* gpA1 = g_bf + jc1 * G_PAD + cA * 8;
  const short* wb0 = W1cT + rA * G_PAD + cA * 8;
  const short* wb1 = W1cT + (rA + 64) * G_PAD + cA * 8;
  const short* wb2 = W1cT + (rA + 128) * G_PAD + cA * 8;  // tid<128 only

  short8 ra0, ra1, rgv, rb0, rb1, rb2;
  auto issue_loads = [&](int s) {
    if (s < NSTEP) {
      const int d0 = s * BK;
      rgv = *(const short8*)(gi_s + d0 + cA * 8);
      ra0 = *(const short8*)(gpA0 + d0);
      ra1 = *(const short8*)(gpA1 + d0);
      rb0 = *(const short8*)(wb0 + d0);
      rb1 = *(const short8*)(wb1 + d0);
      if (tid < 128) rb2 = *(const short8*)(wb2 + d0);
    } else {  // aug step: A = 1-hot indicators, B = deWT (U col added later)
      int bv0 = bin_s[rA], bv1 = bin_s[rA + 64];
      #pragma unroll
      for (int e = 0; e < 8; ++e) {
        int kk = cA * 8 + e;
        ra0[e] = (kk == bv0 || kk == 9) ? (short)0x3F80 : (short)0;
        ra1[e] = (kk == bv1 || kk == 9) ? (short)0x3F80 : (short)0;
        rgv[e] = (short)0x3F80;   // 1.0 -> product passthrough (exact)
      }
      rb0 = *(const short8*)(deWT + rA * BK + cA * 8);
      rb1 = *(const short8*)(deWT + (rA + 64) * BK + cA * 8);
      if (tid < 128) rb2 = *(const short8*)(deWT + (rA + 128) * BK + cA * 8);
    }
  };
  auto write_stage = [&](char* P, char* B) {
    short8 p0, p1;
    #pragma unroll
    for (int e = 0; e < 8; ++e) {
      p0[e] = f2bf_hw(bf2f(ra0[e]) * bf2f(rgv[e]));
      p1[e] = f2bf_hw(bf2f(ra1[e]) * bf2f(rgv[e]));
    }
    *(short8*)(P + rA * PSTR + cA * 16) = p0;
    *(short8*)(P + (rA + 64) * PSTR + cA * 16) = p1;
    *(short8*)(B + rA * PSTR + cA * 16) = rb0;
    *(short8*)(B + (rA + 64) * PSTR + cA * 16) = rb1;
    if (tid < 128) *(short8*)(B + (rA + 128) * PSTR + cA * 16) = rb2;
  };

  const float4_t fz = {0.f, 0.f, 0.f, 0.f};
  float4_t acc[4][5];
  #pragma unroll
  for (int a = 0; a < 4; ++a)
    #pragma unroll
    for (int b = 0; b < 5; ++b) acc[a][b] = fz;

  // prologue: stage step 0
  issue_loads(0);
  write_stage(P0, B0);

  // ---- layer 1: 21 steps (20 data + 1 aug), 1 barrier/step ----
  for (int s = 0; s <= NSTEP; ++s) {
    char* Pc = (s & 1) ? P1 : P0;
    char* Bc = (s & 1) ? B1 : B0;
    char* Pn = (s & 1) ? P0 : P1;
    char* Bn = (s & 1) ? B0 : B1;
    __syncthreads();
    if (s == NSTEP) {   // add per-block U column (kk=9) after staged zeros
      if (tid < H_PAD) *(short*)(Bc + tid * PSTR + 18) = U_bf[i * H_PAD + tid];
      __syncthreads();
    }
    if (s < NSTEP) issue_loads(s + 1);     // issue-early (T14)
    {
      short8 af[4], bq[5];
      #pragma unroll
      for (int mt = 0; mt < 4; ++mt) {
        int row = wm * 64 + mt * 16 + lo4;
        af[mt] = *((const short8*)(Pc + row * PSTR + hi2 * 16));
      }
      #pragma unroll
      for (int nt = 0; nt < 5; ++nt) {
        int row = wn * 80 + nt * 16 + lo4;
        bq[nt] = *((const short8*)(Bc + row * PSTR + hi2 * 16));
      }
      #pragma unroll
      for (int mt = 0; mt < 4; ++mt)
        #pragma unroll
        for (int nt = 0; nt < 5; ++nt)
          acc[mt][nt] = __builtin_amdgcn_mfma_f32_16x16x32_bf16(af[mt], bq[nt], acc[mt][nt], 0, 0, 0);
    }
    if (s < NSTEP) write_stage(Pn, Bn);    // write-late
  }
  __syncthreads();   // layer-1 reads done; Hb may overwrite stage area

  // ---- epilogue 1: h1 = relu(acc + V[j]) -> Hb bf16 swizzled tiles ----
  #pragma unroll
  for (int mt = 0; mt < 4; ++mt) {
    #pragma unroll
    for (int r = 0; r < 4; ++r) {
      int m = wm * 64 + mt * 16 + hi2 * 4 + r;
      int jr = i - K_WIN + m, jc = jr < 0 ? 0 : jr;
      const float* Vj = V + jc * H_PAD;
      #pragma unroll
      for (int nt = 0; nt < 5; ++nt) {
        int h = wn * 80 + nt * 16 + lo4;
        float val = acc[mt][nt][r] + Vj[h];
        val = (h < H_DIM) ? fmaxf(val, 0.f) : 0.f;
        int tile = h >> 6, hc = h & 63;
        int byte = tile * 16384 + m * 128 + ((hc * 2) ^ ((m & 7) << 4));
        *((short*)(Hb + byte)) = f2bf_hw(val);
      }
    }
  }
  // zero tile2 bytes 64..127 (swizzle XOR addresses them for k=128..159 reads)
  {
    short8 z = {0, 0, 0, 0, 0, 0, 0, 0};
    for (int c = tid; c < 512; c += 256) {
      int row = c >> 2, cb = c & 3;
      int byte = 2 * 16384 + row * 128 + ((64 + cb * 16) ^ ((row & 7) << 4));
      *((short8*)(Hb + byte)) = z;
    }
  }
  __syncthreads();

  // ---- layer 2: D2 = h1 @ W2 (K=160), B direct from global (L2) ----
  float4_t acc2[4][5];
  #pragma unroll
  for (int a = 0; a < 4; ++a)
    #pragma unroll
    for (int b = 0; b < 5; ++b) acc2[a][b] = fz;

  short8 bql[2][5];
  #pragma unroll
  for (int nt = 0; nt < 5; ++nt) {
    int row = wn * 80 + nt * 16 + lo4;
    bql[0][nt] = *(const short8*)(W2T + row * H_PAD + hi2 * 8);
  }
  #pragma unroll
  for (int ks = 0; ks < 5; ++ks) {
    const int cur = ks & 1;
    if (ks < 4) {
      #pragma unroll
      for (int nt = 0; nt < 5; ++nt) {
        int row = wn * 80 + nt * 16 + lo4;
        bql[cur ^ 1][nt] = *(const short8*)(W2T + row * H_PAD + (ks + 1) * BK + hi2 * 8);
      }
    }
    short8 af[4];
    #pragma unroll
    for (int mt = 0; mt < 4; ++mt) {
      int row = wm * 64 + mt * 16 + lo4;
      int kb = (ks & 1) * 64 + hi2 * 16;
      af[mt] = *((const short8*)(Hb + (ks >> 1) * 16384 + row * 128 + (kb ^ ((row & 7) << 4))));
    }
    #pragma unroll
    for (int mt = 0; mt < 4; ++mt)
      #pragma unroll
      for (int nt = 0; nt < 5; ++nt)
        acc2[mt][nt] = __builtin_amdgcn_mfma_f32_16x16x32_bf16(af[mt], bql[cur][nt], acc2[mt][nt], 0, 0, 0);
  }

  // ---- epilogue 2: s = relu(acc2 + b2) @ W3, reduce, emit ----
  float sp[4][4];
  #pragma unroll
  for (int mt = 0; mt < 4; ++mt)
    #pragma unroll
    for (int r = 0; r < 4; ++r) sp[mt][r] = 0.f;

  #pragma unroll
  for (int nt = 0; nt < 5; ++nt) {
    int h = wn * 80 + nt * 16 + lo4;
    float w3 = (h < H_DIM) ? W3[h] : 0.f;
    float bb = (h < H_DIM) ? b2[h] : 0.f;
    #pragma unroll
    for (int mt = 0; mt < 4; ++mt)
      #pragma unroll
      for (int r = 0; r < 4; ++r) {
        float hv = fmaxf(acc2[mt][nt][r] + bb, 0.f);
        sp[mt][r] += hv * w3;
      }
  }
  #pragma unroll
  for (int mt = 0; mt < 4; ++mt)
    #pragma unroll
    for (int r = 0; r < 4; ++r) {
      float v = sp[mt][r];
      v += __shfl_xor(v, 1);
      v += __shfl_xor(v, 2);
      v += __shfl_xor(v, 4);
      v += __shfl_xor(v, 8);
      sp[mt][r] = v;
    }
  if (lo4 == 0) {
    #pragma unroll
    for (int mt = 0; mt < 4; ++mt)
      #pragma unroll
      for (int r = 0; r < 4; ++r) {
        int m = wm * 64 + mt * 16 + hi2 * 4 + r;
        s_buf[wn][m] = sp[mt][r];
      }
  }
  __syncthreads();

  if (tid < K_WIN) {
    int m = tid;
    int jr = i - K_WIN + m;
    float sij = si[i] + sj_s[m] + s_buf[0][m] + s_buf[1][m] + b3[0];
    out[i * OUT_C + m] = (jr >= 0) ? sij : 0.f;
  }
  if (tid == K_WIN) out[i * OUT_C + K_WIN] = 0.f;
}

// ---------------------------------------------------------------------------
extern "C" void kernel_launch(void* const* d_in, const int* in_sizes, int n_in,
                              void* d_out, int out_size, void* d_ws, size_t ws_size,
                              hipStream_t stream) {
  const float* g  = (const float*)d_in[0];
  const float* si = (const float*)d_in[1];
  const int*   i1 = (const int*)d_in[2];
  const int*   i2 = (const int*)d_in[3];
  const float* de = (const float*)d_in[4];
  const float* W1 = (const float*)d_in[5];
  const float* b1 = (const float*)d_in[6];
  const float* W2 = (const float*)d_in[7];
  const float* b2 = (const float*)d_in[8];
  const float* W3 = (const float*)d_in[9];
  const float* b3 = (const float*)d_in[10];
  float* out = (float*)d_out;

  char* ws = (char*)d_ws;
  short* g_bf  = (short*)(ws);                 // 1,310,720
  short* W1cT  = (short*)(ws + 1310720);       //   204,800
  short* W1abT = (short*)(ws + 1515520);       //   409,600
  short* W2T   = (short*)(ws + 1925120);       //    51,200
  float* V     = (float*)(ws + 1976320);       //   655,360
  short* U_bf  = (short*)(ws + 2631680);       //   327,680
  short* deWT  = (short*)(ws + 2959360);       //    10,240  (total ~2.97 MB)

  prep_pack<<<321, 256, 0, stream>>>(g, W1, W2, de, g_bf, W1cT, W1abT, W2T, deWT);
  prep_uv_mfma<<<dim3(16, 2), 256, 0, stream>>>(g_bf, W1abT, b1, U_bf, V);
  pair_main<<<N_PTS, 256, 0, stream>>>(g_bf, W1cT, W2T, U_bf, V, deWT,
                                       si, i1, i2, W3, b2, b3, out);
}